// Round 1
// baseline (14935.182 us; speedup 1.0000x reference)
//
#include <hip/hip_runtime.h>
#include <hip/hip_bf16.h>

#define B_   64
#define T_   512
#define E_   300
#define U_   512
#define G4_  2048
#define D1_  1024
#define D2_  1024
#define NC_  20

typedef __bf16 bf16x8 __attribute__((ext_vector_type(8)));
typedef float  f32x4  __attribute__((ext_vector_type(4)));

__device__ __forceinline__ float sigmoidf_(float x) { return 1.0f / (1.0f + __expf(-x)); }

// ---------------------------------------------------------------------------
// init: zero hbuf[0] (64x512 bf16) and flags (256 ints)
// ---------------------------------------------------------------------------
__global__ void init_kernel(unsigned int* __restrict__ hz, int* __restrict__ flags) {
    int idx = blockIdx.x * 256 + threadIdx.x;
    if (idx < (B_ * U_ / 2)) hz[idx] = 0u;
    if (idx < 256) flags[idx] = 0;
}

// ---------------------------------------------------------------------------
// embed + xg GEMM: xg[t][b][n] = sum_e emb[tok[b,t], e] * Wx[e, n] + b[n]
// tile: 32 bt-rows x 64 n-cols per block; f32 VALU, bf16 output
// ---------------------------------------------------------------------------
__global__ __launch_bounds__(256) void embed_xg_kernel(const int* __restrict__ tokens,
                                                       const float* __restrict__ emb,
                                                       const float* __restrict__ Wx,
                                                       const float* __restrict__ bias,
                                                       __hip_bfloat16* __restrict__ xg) {
    const int n0  = blockIdx.x * 64;
    const int bt0 = blockIdx.y * 32;
    __shared__ __align__(16) float xsT[E_][36];   // [e][m], pad 36 to break bank stride
    __shared__ int toks[32];
    const int tid = threadIdx.x;

    if (tid < 32) toks[tid] = tokens[bt0 + tid];
    __syncthreads();
    for (int i = tid; i < 32 * E_; i += 256) {
        int m = i / E_, e = i - m * E_;
        xsT[e][m] = emb[(size_t)toks[m] * E_ + e];
    }
    __syncthreads();

    const int mg = tid >> 5;        // 0..7 -> rows mg*4 .. mg*4+3
    const int ng = tid & 31;        // cols n0 + ng*2, +1
    const int n  = n0 + ng * 2;

    float a00 = 0.f, a01 = 0.f, a10 = 0.f, a11 = 0.f;
    float a20 = 0.f, a21 = 0.f, a30 = 0.f, a31 = 0.f;

    #pragma unroll 2
    for (int e = 0; e < E_; ++e) {
        float2 w  = *(const float2*)&Wx[(size_t)e * G4_ + n];
        float4 xv = *(const float4*)&xsT[e][mg * 4];
        a00 = fmaf(xv.x, w.x, a00);  a01 = fmaf(xv.x, w.y, a01);
        a10 = fmaf(xv.y, w.x, a10);  a11 = fmaf(xv.y, w.y, a11);
        a20 = fmaf(xv.z, w.x, a20);  a21 = fmaf(xv.z, w.y, a21);
        a30 = fmaf(xv.w, w.x, a30);  a31 = fmaf(xv.w, w.y, a31);
    }

    const float b0 = bias[n], b1v = bias[n + 1];
    float r0[4] = {a00, a10, a20, a30};
    float r1[4] = {a01, a11, a21, a31};
    #pragma unroll
    for (int r = 0; r < 4; ++r) {
        int bt = bt0 + mg * 4 + r;
        int bb = bt >> 9, tt = bt & 511;
        __hip_bfloat16* dst = xg + (size_t)(tt * B_ + bb) * G4_ + n;
        dst[0] = __float2bfloat16(r0[r] + b0);
        dst[1] = __float2bfloat16(r1[r] + b1v);
    }
}

// ---------------------------------------------------------------------------
// LSTM: 256 blocks = 64 unit-slices x 4 batch-groups; weight-stationary in LDS
// ---------------------------------------------------------------------------
__global__ __launch_bounds__(256) void lstm_kernel(const __hip_bfloat16* __restrict__ xg,
                                                   const int* __restrict__ tokens,
                                                   const float* __restrict__ Wh,
                                                   __hip_bfloat16* __restrict__ hbuf,
                                                   int* __restrict__ flags) {
    const int tid  = threadIdx.x;
    const int lane = tid & 63;
    const int wave = tid >> 6;
    const int ub   = blockIdx.x & 63;   // unit-slice: units [ub*8, ub*8+8)
    const int g    = blockIdx.x >> 6;   // batch-group: batches [g*16, g*16+16)
    const int u0   = ub * 8;

    __shared__ __align__(16) __hip_bfloat16 whsT[32][520];  // [c][k], c = q*8+j
    __shared__ __align__(16) __hip_bfloat16 hs[16][520];    // [m][k]
    __shared__ float gbuf[16][32];

    // load Wh slice (bf16, column-major over k for b128 frag reads)
    for (int idx = tid; idx < 32 * 512; idx += 256) {
        int c = idx & 31, k = idx >> 5;
        int col = ((c >> 3) << 9) + u0 + (c & 7);
        whsT[c][k] = __float2bfloat16(Wh[(size_t)k * G4_ + col]);
    }

    float creg = 0.f, hreg = 0.f;
    const int bloc = tid >> 3, uloc = tid & 7;   // update threads (tid<128)
    int* gflags = flags + g * 64;

    // per-lane fragment addressing (constant across steps)
    const int fn   = lane & 15;
    const int quad = lane >> 4;
    const int fc   = wave * 16 + fn;                         // col 0..31 (waves 0,1)
    const int fcol = ((fc >> 3) << 9) + u0 + (fc & 7);       // global gate col

    __syncthreads();

    for (int s = 0; s < T_; ++s) {
        if (s > 0) {
            if (tid < 64) {
                while (__hip_atomic_load(&gflags[tid], __ATOMIC_RELAXED,
                                         __HIP_MEMORY_SCOPE_AGENT) < s)
                    __builtin_amdgcn_s_sleep(1);
            }
            __syncthreads();
            __threadfence();   // acquire: invalidate stale L1/L2 before reading peers' h
        }

        // issue xg loads early (independent of h staging)
        f32x4 acc;
        if (wave < 2) {
            #pragma unroll
            for (int r = 0; r < 4; ++r) {
                int bglob = g * 16 + quad * 4 + r;
                acc[r] = __bfloat162float(xg[(size_t)(s * B_ + bglob) * G4_ + fcol]);
            }
        }

        // stage h (16 batches x 512 units, bf16) from hbuf[s&1]
        {
            const __hip_bfloat16* hr = hbuf + (size_t)((s & 1) * B_ + g * 16) * U_;
            #pragma unroll
            for (int i = 0; i < 4; ++i) {
                int idx = tid + i * 256;
                int m = idx >> 6, p = idx & 63;
                ((uint4*)(&hs[m][0]))[p] = ((const uint4*)(hr + m * U_))[p];
            }
        }
        __syncthreads();

        if (wave < 2) {
            const __hip_bfloat16* arow = &hs[fn][quad * 8];     // A[m=lane&15][k=quad*8+j]
            const __hip_bfloat16* brow = &whsT[fc][quad * 8];   // B[k][n=lane&15]
            #pragma unroll
            for (int kk = 0; kk < 16; ++kk) {
                bf16x8 av = *(const bf16x8*)(arow + kk * 32);
                bf16x8 bv = *(const bf16x8*)(brow + kk * 32);
                acc = __builtin_amdgcn_mfma_f32_16x16x32_bf16(av, bv, acc, 0, 0, 0);
            }
            #pragma unroll
            for (int r = 0; r < 4; ++r)                          // D: row=quad*4+r, col=lane&15
                gbuf[quad * 4 + r][fc] = acc[r];
        }
        __syncthreads();

        if (tid < 128) {
            float gi = gbuf[bloc][uloc];
            float gf = gbuf[bloc][8 + uloc];
            float gc = gbuf[bloc][16 + uloc];
            float go = gbuf[bloc][24 + uloc];
            gi = sigmoidf_(gi); gf = sigmoidf_(gf); go = sigmoidf_(go);
            float cn = gf * creg + gi * fmaxf(gc, 0.f);
            float hn = go * fmaxf(cn, 0.f);
            int tok = tokens[(g * 16 + bloc) * T_ + s];
            if (tok != 0) { creg = cn; hreg = hn; }
            hbuf[(size_t)(((s + 1) & 1) * B_ + g * 16 + bloc) * U_ + u0 + uloc] =
                __float2bfloat16(hreg);
        }
        __syncthreads();   // all h stores done (barrier drains vmcnt) before flag release
        if (tid == 0)
            __hip_atomic_store(&gflags[ub], s + 1, __ATOMIC_RELEASE,
                               __HIP_MEMORY_SCOPE_AGENT);
    }
}

// ---------------------------------------------------------------------------
// FC layers
// ---------------------------------------------------------------------------
__global__ __launch_bounds__(256) void fc1_kernel(const __hip_bfloat16* __restrict__ h,
                                                  const float* __restrict__ W,
                                                  const float* __restrict__ bias,
                                                  float* __restrict__ y) {
    int b = blockIdx.x >> 2, ch = blockIdx.x & 3;
    __shared__ float xrow[U_];
    for (int i = threadIdx.x; i < U_; i += 256)
        xrow[i] = __bfloat162float(h[b * U_ + i]);
    __syncthreads();
    int n = ch * 256 + threadIdx.x;
    float acc = 0.f;
    #pragma unroll 4
    for (int k = 0; k < U_; ++k) acc = fmaf(xrow[k], W[(size_t)k * D1_ + n], acc);
    y[b * D1_ + n] = fmaxf(acc + bias[n], 0.f);
}

__global__ __launch_bounds__(256) void fc2_kernel(const float* __restrict__ x,
                                                  const float* __restrict__ W,
                                                  const float* __restrict__ bias,
                                                  float* __restrict__ y) {
    int b = blockIdx.x >> 2, ch = blockIdx.x & 3;
    __shared__ float xrow[D1_];
    for (int i = threadIdx.x; i < D1_; i += 256) xrow[i] = x[b * D1_ + i];
    __syncthreads();
    int n = ch * 256 + threadIdx.x;
    float acc = 0.f;
    #pragma unroll 4
    for (int k = 0; k < D1_; ++k) acc = fmaf(xrow[k], W[(size_t)k * D2_ + n], acc);
    y[b * D2_ + n] = fmaxf(acc + bias[n], 0.f);
}

// ---------------------------------------------------------------------------
// logits + softmax
// ---------------------------------------------------------------------------
__global__ __launch_bounds__(64) void out_kernel(const float* __restrict__ h2,
                                                 const float* __restrict__ Wo,
                                                 const float* __restrict__ bo,
                                                 float* __restrict__ out) {
    int b = blockIdx.x;
    __shared__ float xrow[D2_];
    __shared__ float lg[NC_];
    __shared__ float red[2];
    for (int i = threadIdx.x; i < D2_; i += 64) xrow[i] = h2[b * D2_ + i];
    __syncthreads();
    if (threadIdx.x < NC_) {
        float a = bo[threadIdx.x];
        for (int k = 0; k < D2_; ++k) a = fmaf(xrow[k], Wo[k * NC_ + threadIdx.x], a);
        lg[threadIdx.x] = a;
    }
    __syncthreads();
    if (threadIdx.x == 0) {
        float mx = lg[0];
        for (int c = 1; c < NC_; ++c) mx = fmaxf(mx, lg[c]);
        float sm = 0.f;
        for (int c = 0; c < NC_; ++c) sm += expf(lg[c] - mx);
        red[0] = mx; red[1] = 1.0f / sm;
    }
    __syncthreads();
    if (threadIdx.x < NC_)
        out[b * NC_ + threadIdx.x] = expf(lg[threadIdx.x] - red[0]) * red[1];
}

// ---------------------------------------------------------------------------
extern "C" void kernel_launch(void* const* d_in, const int* in_sizes, int n_in,
                              void* d_out, int out_size, void* d_ws, size_t ws_size,
                              hipStream_t stream) {
    const int*   tokens = (const int*)d_in[0];
    const float* emb    = (const float*)d_in[1];
    const float* Wx     = (const float*)d_in[2];
    const float* Wh     = (const float*)d_in[3];
    const float* b      = (const float*)d_in[4];
    const float* W1     = (const float*)d_in[5];
    const float* b1     = (const float*)d_in[6];
    const float* W2     = (const float*)d_in[7];
    const float* b2     = (const float*)d_in[8];
    const float* Wo     = (const float*)d_in[9];
    const float* bo     = (const float*)d_in[10];
    float* out = (float*)d_out;

    char* ws = (char*)d_ws;
    const size_t XG_BYTES   = (size_t)T_ * B_ * G4_ * 2;        // 134217728
    const size_t HBUF_BYTES = (size_t)2 * B_ * U_ * 2;          // 131072
    __hip_bfloat16* xg   = (__hip_bfloat16*)ws;
    __hip_bfloat16* hbuf = (__hip_bfloat16*)(ws + XG_BYTES);
    int* flags           = (int*)(ws + XG_BYTES + HBUF_BYTES);
    float* h1            = (float*)(ws + XG_BYTES + HBUF_BYTES + 1024);
    float* h2            = (float*)(ws + XG_BYTES + HBUF_BYTES + 1024 + (size_t)B_ * D1_ * 4);

    init_kernel<<<64, 256, 0, stream>>>((unsigned int*)hbuf, flags);
    embed_xg_kernel<<<dim3(32, 1024), 256, 0, stream>>>(tokens, emb, Wx, b, xg);
    lstm_kernel<<<256, 256, 0, stream>>>(xg, tokens, Wh, hbuf, flags);
    fc1_kernel<<<256, 256, 0, stream>>>(hbuf, W1, b1, h1);
    fc2_kernel<<<256, 256, 0, stream>>>(h1, W2, b2, h2);
    out_kernel<<<64, 64, 0, stream>>>(h2, Wo, bo, out);
}

// Round 2
// 2902.527 us; speedup vs baseline: 5.1456x; 5.1456x over previous
//
#include <hip/hip_runtime.h>
#include <hip/hip_bf16.h>

#define B_   64
#define T_   512
#define E_   300
#define U_   512
#define G4_  2048
#define D1_  1024
#define D2_  1024
#define NC_  20

typedef __bf16 bf16x8 __attribute__((ext_vector_type(8)));
typedef float  f32x4  __attribute__((ext_vector_type(4)));

__device__ __forceinline__ float sigmoidf_(float x) { return 1.0f / (1.0f + __expf(-x)); }

// ---------------------------------------------------------------------------
// init: zero hbuf[0] (64x512 bf16) and flags (256 ints)
// ---------------------------------------------------------------------------
__global__ void init_kernel(unsigned int* __restrict__ hz, int* __restrict__ flags) {
    int idx = blockIdx.x * 256 + threadIdx.x;
    if (idx < (B_ * U_ / 2)) hz[idx] = 0u;
    if (idx < 256) flags[idx] = 0;
}

// ---------------------------------------------------------------------------
// embed + xg GEMM: xg[t][b][n] = sum_e emb[tok[b,t], e] * Wx[e, n] + b[n]
// ---------------------------------------------------------------------------
__global__ __launch_bounds__(256) void embed_xg_kernel(const int* __restrict__ tokens,
                                                       const float* __restrict__ emb,
                                                       const float* __restrict__ Wx,
                                                       const float* __restrict__ bias,
                                                       __hip_bfloat16* __restrict__ xg) {
    const int n0  = blockIdx.x * 64;
    const int bt0 = blockIdx.y * 32;
    __shared__ __align__(16) float xsT[E_][36];
    __shared__ int toks[32];
    const int tid = threadIdx.x;

    if (tid < 32) toks[tid] = tokens[bt0 + tid];
    __syncthreads();
    for (int i = tid; i < 32 * E_; i += 256) {
        int m = i / E_, e = i - m * E_;
        xsT[e][m] = emb[(size_t)toks[m] * E_ + e];
    }
    __syncthreads();

    const int mg = tid >> 5;
    const int ng = tid & 31;
    const int n  = n0 + ng * 2;

    float a00 = 0.f, a01 = 0.f, a10 = 0.f, a11 = 0.f;
    float a20 = 0.f, a21 = 0.f, a30 = 0.f, a31 = 0.f;

    #pragma unroll 2
    for (int e = 0; e < E_; ++e) {
        float2 w  = *(const float2*)&Wx[(size_t)e * G4_ + n];
        float4 xv = *(const float4*)&xsT[e][mg * 4];
        a00 = fmaf(xv.x, w.x, a00);  a01 = fmaf(xv.x, w.y, a01);
        a10 = fmaf(xv.y, w.x, a10);  a11 = fmaf(xv.y, w.y, a11);
        a20 = fmaf(xv.z, w.x, a20);  a21 = fmaf(xv.z, w.y, a21);
        a30 = fmaf(xv.w, w.x, a30);  a31 = fmaf(xv.w, w.y, a31);
    }

    const float b0 = bias[n], b1v = bias[n + 1];
    float r0[4] = {a00, a10, a20, a30};
    float r1[4] = {a01, a11, a21, a31};
    #pragma unroll
    for (int r = 0; r < 4; ++r) {
        int bt = bt0 + mg * 4 + r;
        int bb = bt >> 9, tt = bt & 511;
        __hip_bfloat16* dst = xg + (size_t)(tt * B_ + bb) * G4_ + n;
        dst[0] = __float2bfloat16(r0[r] + b0);
        dst[1] = __float2bfloat16(r1[r] + b1v);
    }
}

// ---------------------------------------------------------------------------
// LSTM: 256 blocks = 64 unit-slices x 4 batch-groups; weight-stationary.
// Cross-block h exchange via coherent (L2-bypass) loads/stores only —
// NO threadfence / NO acquire-release (those emit buffer_inv / buffer_wbl2).
// ---------------------------------------------------------------------------
__global__ __launch_bounds__(256) void lstm_kernel(const __hip_bfloat16* __restrict__ xg,
                                                   const int* __restrict__ tokens,
                                                   const float* __restrict__ Wh,
                                                   __hip_bfloat16* __restrict__ hbuf,
                                                   int* __restrict__ flags) {
    const int tid  = threadIdx.x;
    const int lane = tid & 63;
    const int wave = tid >> 6;
    // XCD swizzle: the 8 blocks sharing xg/Wh cache lines (ub in same group
    // of 8) land on the same XCD (blockIdx % 8 heuristic).
    const int x  = blockIdx.x & 7;
    const int r_ = blockIdx.x >> 3;
    const int ub = x * 8 + (r_ & 7);    // unit-slice: units [ub*8, ub*8+8)
    const int g  = r_ >> 3;             // batch-group: batches [g*16, g*16+16)
    const int u0 = ub * 8;

    __shared__ __align__(16) __hip_bfloat16 whsT[32][520];  // [c][k]
    __shared__ __align__(16) __hip_bfloat16 hs[16][520];    // [m][k]
    __shared__ float gbuf[16][32];
    __shared__ unsigned mask_lds[16][16];                   // token!=0 bitmask

    // load Wh slice (bf16)
    for (int idx = tid; idx < 32 * 512; idx += 256) {
        int c = idx & 31, k = idx >> 5;
        int col = ((c >> 3) << 9) + u0 + (c & 7);
        whsT[c][k] = __float2bfloat16(Wh[(size_t)k * G4_ + col]);
    }
    // precompute per-batch step masks (takes tokens off the serial path)
    {
        int m = tid >> 4, w = tid & 15;
        const int4* tp = (const int4*)(tokens + (size_t)(g * 16 + m) * T_ + w * 32);
        unsigned bits = 0;
        #pragma unroll
        for (int q = 0; q < 8; ++q) {
            int4 v = tp[q];
            bits |= (v.x != 0 ? 1u : 0u) << (q * 4 + 0);
            bits |= (v.y != 0 ? 1u : 0u) << (q * 4 + 1);
            bits |= (v.z != 0 ? 1u : 0u) << (q * 4 + 2);
            bits |= (v.w != 0 ? 1u : 0u) << (q * 4 + 3);
        }
        mask_lds[m][w] = bits;
    }

    float c0 = 0.f, c1 = 0.f, h0 = 0.f, h1 = 0.f;   // update threads (tid<64): 2 units each
    int* gflags = flags + g * 64;

    // per-lane fragment addressing (constant across steps)
    const int fn   = lane & 15;
    const int quad = lane >> 4;
    const int fc   = wave * 16 + fn;                         // gate col 0..31 (waves 0,1)
    const int fcol = ((fc >> 3) << 9) + u0 + (fc & 7);       // global gate col

    __syncthreads();

    for (int s = 0; s < T_; ++s) {
        // xg prefetch (independent of peers) — issue before the flag wait
        float xv[4];
        if (wave < 2) {
            #pragma unroll
            for (int r = 0; r < 4; ++r)
                xv[r] = __bfloat162float(
                    xg[(size_t)(s * B_ + g * 16 + quad * 4 + r) * G4_ + fcol]);
        }

        if (s > 0) {
            if (tid < 64) {
                while (__hip_atomic_load(&gflags[tid], __ATOMIC_RELAXED,
                                         __HIP_MEMORY_SCOPE_AGENT) < s)
                    __builtin_amdgcn_s_sleep(2);
            }
            __syncthreads();
        }

        // stage h (16 batches x 512 units bf16 = 16 KB) with coherent loads,
        // batched under a single vmcnt(0) so they pipeline.
        {
            const uint4* hp = (const uint4*)(hbuf + (size_t)((s & 1) * B_ + g * 16) * U_);
            uint4 t0, t1, t2, t3;
            asm volatile(
                "global_load_dwordx4 %0, %4, off sc0 sc1\n\t"
                "global_load_dwordx4 %1, %5, off sc0 sc1\n\t"
                "global_load_dwordx4 %2, %6, off sc0 sc1\n\t"
                "global_load_dwordx4 %3, %7, off sc0 sc1\n\t"
                "s_waitcnt vmcnt(0)"
                : "=&v"(t0), "=&v"(t1), "=&v"(t2), "=&v"(t3)
                : "v"(hp + tid), "v"(hp + tid + 256), "v"(hp + tid + 512),
                  "v"(hp + tid + 768)
                : "memory");
            int i0 = tid;        *((uint4*)&hs[i0 >> 6][(i0 & 63) * 8]) = t0;
            int i1 = tid + 256;  *((uint4*)&hs[i1 >> 6][(i1 & 63) * 8]) = t1;
            int i2 = tid + 512;  *((uint4*)&hs[i2 >> 6][(i2 & 63) * 8]) = t2;
            int i3 = tid + 768;  *((uint4*)&hs[i3 >> 6][(i3 & 63) * 8]) = t3;
        }
        __syncthreads();

        if (wave < 2) {
            f32x4 acc;
            #pragma unroll
            for (int r = 0; r < 4; ++r) acc[r] = xv[r];
            const __hip_bfloat16* arow = &hs[fn][quad * 8];     // A[m][k=quad*8+j]
            const __hip_bfloat16* brow = &whsT[fc][quad * 8];   // B[k][n]
            #pragma unroll
            for (int kk = 0; kk < 16; ++kk) {
                bf16x8 av = *(const bf16x8*)(arow + kk * 32);
                bf16x8 bv = *(const bf16x8*)(brow + kk * 32);
                acc = __builtin_amdgcn_mfma_f32_16x16x32_bf16(av, bv, acc, 0, 0, 0);
            }
            #pragma unroll
            for (int r = 0; r < 4; ++r)                          // D: row=quad*4+r, col=lane&15
                gbuf[quad * 4 + r][fc] = acc[r];
        }
        __syncthreads();

        if (tid < 64) {
            const int m  = tid >> 2;
            const int u2 = (tid & 3) << 1;
            float gi0 = sigmoidf_(gbuf[m][u2]),      gi1 = sigmoidf_(gbuf[m][u2 + 1]);
            float gf0 = sigmoidf_(gbuf[m][8 + u2]),  gf1 = sigmoidf_(gbuf[m][9 + u2]);
            float gc0 = gbuf[m][16 + u2],            gc1 = gbuf[m][17 + u2];
            float go0 = sigmoidf_(gbuf[m][24 + u2]), go1 = sigmoidf_(gbuf[m][25 + u2]);
            float cn0 = gf0 * c0 + gi0 * fmaxf(gc0, 0.f);
            float cn1 = gf1 * c1 + gi1 * fmaxf(gc1, 0.f);
            float hn0 = go0 * fmaxf(cn0, 0.f);
            float hn1 = go1 * fmaxf(cn1, 0.f);
            if ((mask_lds[m][s >> 5] >> (s & 31)) & 1u) {
                c0 = cn0; c1 = cn1; h0 = hn0; h1 = hn1;
            }
            __hip_bfloat162 hv;
            hv.x = __float2bfloat16(h0);
            hv.y = __float2bfloat16(h1);
            unsigned w;
            __builtin_memcpy(&w, &hv, 4);
            unsigned* dst = (unsigned*)hbuf +
                (((((s + 1) & 1) * B_ + g * 16 + m) * U_ + u0 + u2) >> 1);
            __hip_atomic_store(dst, w, __ATOMIC_RELAXED, __HIP_MEMORY_SCOPE_AGENT);
        }
        __syncthreads();   // implicit vmcnt(0): all h store-acks drained (release)
        if (tid == 0)
            __hip_atomic_store(&gflags[ub], s + 1, __ATOMIC_RELAXED,
                               __HIP_MEMORY_SCOPE_AGENT);
    }
}

// ---------------------------------------------------------------------------
// FC layers
// ---------------------------------------------------------------------------
__global__ __launch_bounds__(256) void fc1_kernel(const __hip_bfloat16* __restrict__ h,
                                                  const float* __restrict__ W,
                                                  const float* __restrict__ bias,
                                                  float* __restrict__ y) {
    int b = blockIdx.x >> 2, ch = blockIdx.x & 3;
    __shared__ float xrow[U_];
    for (int i = threadIdx.x; i < U_; i += 256)
        xrow[i] = __bfloat162float(h[b * U_ + i]);
    __syncthreads();
    int n = ch * 256 + threadIdx.x;
    float acc = 0.f;
    #pragma unroll 4
    for (int k = 0; k < U_; ++k) acc = fmaf(xrow[k], W[(size_t)k * D1_ + n], acc);
    y[b * D1_ + n] = fmaxf(acc + bias[n], 0.f);
}

__global__ __launch_bounds__(256) void fc2_kernel(const float* __restrict__ x,
                                                  const float* __restrict__ W,
                                                  const float* __restrict__ bias,
                                                  float* __restrict__ y) {
    int b = blockIdx.x >> 2, ch = blockIdx.x & 3;
    __shared__ float xrow[D1_];
    for (int i = threadIdx.x; i < D1_; i += 256) xrow[i] = x[b * D1_ + i];
    __syncthreads();
    int n = ch * 256 + threadIdx.x;
    float acc = 0.f;
    #pragma unroll 4
    for (int k = 0; k < D1_; ++k) acc = fmaf(xrow[k], W[(size_t)k * D2_ + n], acc);
    y[b * D2_ + n] = fmaxf(acc + bias[n], 0.f);
}

// ---------------------------------------------------------------------------
// logits + softmax
// ---------------------------------------------------------------------------
__global__ __launch_bounds__(64) void out_kernel(const float* __restrict__ h2,
                                                 const float* __restrict__ Wo,
                                                 const float* __restrict__ bo,
                                                 float* __restrict__ out) {
    int b = blockIdx.x;
    __shared__ float xrow[D2_];
    __shared__ float lg[NC_];
    __shared__ float red[2];
    for (int i = threadIdx.x; i < D2_; i += 64) xrow[i] = h2[b * D2_ + i];
    __syncthreads();
    if (threadIdx.x < NC_) {
        float a = bo[threadIdx.x];
        for (int k = 0; k < D2_; ++k) a = fmaf(xrow[k], Wo[k * NC_ + threadIdx.x], a);
        lg[threadIdx.x] = a;
    }
    __syncthreads();
    if (threadIdx.x == 0) {
        float mx = lg[0];
        for (int c = 1; c < NC_; ++c) mx = fmaxf(mx, lg[c]);
        float sm = 0.f;
        for (int c = 0; c < NC_; ++c) sm += expf(lg[c] - mx);
        red[0] = mx; red[1] = 1.0f / sm;
    }
    __syncthreads();
    if (threadIdx.x < NC_)
        out[b * NC_ + threadIdx.x] = expf(lg[threadIdx.x] - red[0]) * red[1];
}

// ---------------------------------------------------------------------------
extern "C" void kernel_launch(void* const* d_in, const int* in_sizes, int n_in,
                              void* d_out, int out_size, void* d_ws, size_t ws_size,
                              hipStream_t stream) {
    const int*   tokens = (const int*)d_in[0];
    const float* emb    = (const float*)d_in[1];
    const float* Wx     = (const float*)d_in[2];
    const float* Wh     = (const float*)d_in[3];
    const float* b      = (const float*)d_in[4];
    const float* W1     = (const float*)d_in[5];
    const float* b1     = (const float*)d_in[6];
    const float* W2     = (const float*)d_in[7];
    const float* b2     = (const float*)d_in[8];
    const float* Wo     = (const float*)d_in[9];
    const float* bo     = (const float*)d_in[10];
    float* out = (float*)d_out;

    char* ws = (char*)d_ws;
    const size_t XG_BYTES   = (size_t)T_ * B_ * G4_ * 2;        // 134217728
    const size_t HBUF_BYTES = (size_t)2 * B_ * U_ * 2;          // 131072
    __hip_bfloat16* xg   = (__hip_bfloat16*)ws;
    __hip_bfloat16* hbuf = (__hip_bfloat16*)(ws + XG_BYTES);
    int* flags           = (int*)(ws + XG_BYTES + HBUF_BYTES);
    float* h1            = (float*)(ws + XG_BYTES + HBUF_BYTES + 1024);
    float* h2            = (float*)(ws + XG_BYTES + HBUF_BYTES + 1024 + (size_t)B_ * D1_ * 4);

    init_kernel<<<64, 256, 0, stream>>>((unsigned int*)hbuf, flags);
    embed_xg_kernel<<<dim3(32, 1024), 256, 0, stream>>>(tokens, emb, Wx, b, xg);
    lstm_kernel<<<256, 256, 0, stream>>>(xg, tokens, Wh, hbuf, flags);
    fc1_kernel<<<256, 256, 0, stream>>>(hbuf, W1, b1, h1);
    fc2_kernel<<<256, 256, 0, stream>>>(h1, W2, b2, h2);
    out_kernel<<<64, 64, 0, stream>>>(h2, Wo, bo, out);
}

// Round 3
// 1655.230 us; speedup vs baseline: 9.0230x; 1.7535x over previous
//
#include <hip/hip_runtime.h>
#include <hip/hip_bf16.h>

#define B_   64
#define T_   512
#define E_   300
#define U_   512
#define G4_  2048
#define D1_  1024
#define D2_  1024
#define NC_  20
#define KP_  320          // E_ padded to multiple of 32 for MFMA

typedef __bf16 bf16x8 __attribute__((ext_vector_type(8)));
typedef float  f32x4  __attribute__((ext_vector_type(4)));

__device__ __forceinline__ float sigmoidf_(float x) { return 1.0f / (1.0f + __expf(-x)); }

__device__ __forceinline__ void gl_lds16(const void* g, void* l) {
    __builtin_amdgcn_global_load_lds(
        (const __attribute__((address_space(1))) unsigned int*)g,
        (__attribute__((address_space(3))) unsigned int*)l, 16, 0, 0);
}

// ---------------------------------------------------------------------------
// init: zero hbuf[0] (64x512 bf16) and flags (256 ints)
// ---------------------------------------------------------------------------
__global__ void init_kernel(unsigned int* __restrict__ hz, int* __restrict__ flags) {
    int idx = blockIdx.x * 256 + threadIdx.x;
    if (idx < (B_ * U_ / 2)) hz[idx] = 0u;
    if (idx < 256) flags[idx] = 0;
}

// ---------------------------------------------------------------------------
// prep: Wx (300x2048 f32) -> WxT[2048][320] bf16 (transposed, K zero-padded)
// ---------------------------------------------------------------------------
__global__ __launch_bounds__(256) void prep_wxT(const float* __restrict__ Wx,
                                                __hip_bfloat16* __restrict__ wxT) {
    __shared__ __hip_bfloat16 t[64][65];
    const int n0 = blockIdx.x * 64;   // 32 tiles
    const int k0 = blockIdx.y * 64;   // 5 tiles
    const int tid = threadIdx.x;
    for (int i = tid; i < 4096; i += 256) {
        int r = i >> 6, c = i & 63;                 // r = k-local, c = n-local
        int k = k0 + r;
        float v = (k < E_) ? Wx[(size_t)k * G4_ + n0 + c] : 0.f;
        t[r][c] = __float2bfloat16(v);
    }
    __syncthreads();
    for (int i = tid; i < 4096; i += 256) {
        int r = i >> 6, c = i & 63;                 // r = n-local, c = k-local
        wxT[(size_t)(n0 + r) * KP_ + k0 + c] = t[c][r];
    }
}

// ---------------------------------------------------------------------------
// prep: gather + cvt  xb[bt][k] = bf16(emb[tokens[bt]][k]), zero-padded K
// ---------------------------------------------------------------------------
__global__ __launch_bounds__(256) void prep_xb(const int* __restrict__ tokens,
                                               const float* __restrict__ emb,
                                               __hip_bfloat16* __restrict__ xb) {
    const int row = blockIdx.x * 4 + (threadIdx.x >> 6);
    const int ln  = threadIdx.x & 63;
    const int tok = tokens[row];
    const float* src = emb + (size_t)tok * E_;
    __hip_bfloat16* dst = xb + (size_t)row * KP_;
    for (int k = ln; k < KP_; k += 64)
        dst[k] = (k < E_) ? __float2bfloat16(src[k]) : __float2bfloat16(0.f);
}

// ---------------------------------------------------------------------------
// xg GEMM (MFMA): xg[t][b][n] = xb[bt] @ WxT^T + bias   (m97-style 128x128)
// ---------------------------------------------------------------------------
__global__ __launch_bounds__(256) void xg_gemm(const __hip_bfloat16* __restrict__ xb,
                                               const __hip_bfloat16* __restrict__ wxT,
                                               const float* __restrict__ bias,
                                               __hip_bfloat16* __restrict__ xg) {
    const int n0g = blockIdx.x * 128;   // 16
    const int bt0 = blockIdx.y * 128;   // 256
    const int tid = threadIdx.x;
    const int w   = tid >> 6;
    const int ln  = tid & 63;
    const int fn  = ln & 15;
    const int quad = ln >> 4;
    const int m0  = (w >> 1) * 64;
    const int n0w = (w & 1) * 64;

    __shared__ __align__(16) __hip_bfloat16 As[128 * 32];
    __shared__ __align__(16) __hip_bfloat16 Bs[128 * 32];

    f32x4 acc[4][4];
    #pragma unroll
    for (int im = 0; im < 4; ++im)
        #pragma unroll
        for (int in = 0; in < 4; ++in)
            acc[im][in] = (f32x4){0.f, 0.f, 0.f, 0.f};

    // staging addresses (per k-step add 32 elements)
    const __hip_bfloat16* ga = xb  + (size_t)(bt0 + w * 32 + (ln >> 2)) * KP_ + (ln & 3) * 8;
    const __hip_bfloat16* gb = wxT + (size_t)(n0g + w * 32 + (ln >> 2)) * KP_ + (ln & 3) * 8;

    for (int kt = 0; kt < KP_ / 32; ++kt) {
        gl_lds16(ga,             &As[(w * 32) * 32]);
        gl_lds16(ga + 16 * KP_,  &As[(w * 32 + 16) * 32]);
        gl_lds16(gb,             &Bs[(w * 32) * 32]);
        gl_lds16(gb + 16 * KP_,  &Bs[(w * 32 + 16) * 32]);
        ga += 32; gb += 32;
        __syncthreads();

        bf16x8 af[4], bf[4];
        #pragma unroll
        for (int im = 0; im < 4; ++im)
            af[im] = *(const bf16x8*)&As[(m0 + im * 16 + fn) * 32 + quad * 8];
        #pragma unroll
        for (int in = 0; in < 4; ++in)
            bf[in] = *(const bf16x8*)&Bs[(n0w + in * 16 + fn) * 32 + quad * 8];
        #pragma unroll
        for (int im = 0; im < 4; ++im)
            #pragma unroll
            for (int in = 0; in < 4; ++in)
                acc[im][in] = __builtin_amdgcn_mfma_f32_16x16x32_bf16(
                    af[im], bf[in], acc[im][in], 0, 0, 0);
        __syncthreads();
    }

    // epilogue: D lane holds rows quad*4+r, col fn of each 16x16 tile
    #pragma unroll
    for (int in = 0; in < 4; ++in) {
        const int n = n0g + n0w + in * 16 + fn;
        const float bv = bias[n];
        #pragma unroll
        for (int im = 0; im < 4; ++im) {
            #pragma unroll
            for (int r = 0; r < 4; ++r) {
                int m = bt0 + m0 + im * 16 + quad * 4 + r;   // bt = b*T + t
                int bb = m >> 9, tt = m & 511;
                xg[(size_t)(tt * B_ + bb) * G4_ + n] =
                    __float2bfloat16(acc[im][in][r] + bv);
            }
        }
    }
}

// ---------------------------------------------------------------------------
// LSTM: 256 blocks = 64 unit-slices x 4 batch-groups; weight-stationary.
// Cross-block h exchange via coherent (L2-bypass) loads/stores only.
// ---------------------------------------------------------------------------
__global__ __launch_bounds__(256) void lstm_kernel(const __hip_bfloat16* __restrict__ xg,
                                                   const int* __restrict__ tokens,
                                                   const float* __restrict__ Wh,
                                                   __hip_bfloat16* __restrict__ hbuf,
                                                   int* __restrict__ flags) {
    const int tid  = threadIdx.x;
    const int lane = tid & 63;
    const int wave = tid >> 6;
    const int x  = blockIdx.x & 7;
    const int r_ = blockIdx.x >> 3;
    const int ub = x * 8 + (r_ & 7);    // unit-slice: units [ub*8, ub*8+8)
    const int g  = r_ >> 3;             // batch-group: batches [g*16, g*16+16)
    const int u0 = ub * 8;

    __shared__ __align__(16) __hip_bfloat16 whsT[32][520];  // [c][k]
    __shared__ __align__(16) __hip_bfloat16 hs[16][520];    // [m][k]
    __shared__ float gbuf[16][32];
    __shared__ unsigned mask_lds[16][16];                   // token!=0 bitmask

    for (int idx = tid; idx < 32 * 512; idx += 256) {
        int c = idx & 31, k = idx >> 5;
        int col = ((c >> 3) << 9) + u0 + (c & 7);
        whsT[c][k] = __float2bfloat16(Wh[(size_t)k * G4_ + col]);
    }
    {
        int m = tid >> 4, wi = tid & 15;
        const int4* tp = (const int4*)(tokens + (size_t)(g * 16 + m) * T_ + wi * 32);
        unsigned bits = 0;
        #pragma unroll
        for (int q = 0; q < 8; ++q) {
            int4 v = tp[q];
            bits |= (v.x != 0 ? 1u : 0u) << (q * 4 + 0);
            bits |= (v.y != 0 ? 1u : 0u) << (q * 4 + 1);
            bits |= (v.z != 0 ? 1u : 0u) << (q * 4 + 2);
            bits |= (v.w != 0 ? 1u : 0u) << (q * 4 + 3);
        }
        mask_lds[m][wi] = bits;
    }

    float c0 = 0.f, c1 = 0.f, h0 = 0.f, h1 = 0.f;
    int* gflags = flags + g * 64;

    const int fn   = lane & 15;
    const int quad = lane >> 4;
    const int fc   = wave * 16 + fn;
    const int fcol = ((fc >> 3) << 9) + u0 + (fc & 7);

    __syncthreads();

    for (int s = 0; s < T_; ++s) {
        float xv[4];
        if (wave < 2) {
            #pragma unroll
            for (int r = 0; r < 4; ++r)
                xv[r] = __bfloat162float(
                    xg[(size_t)(s * B_ + g * 16 + quad * 4 + r) * G4_ + fcol]);
        }

        if (s > 0) {
            if (tid < 64) {
                while (__hip_atomic_load(&gflags[tid], __ATOMIC_RELAXED,
                                         __HIP_MEMORY_SCOPE_AGENT) < s)
                    __builtin_amdgcn_s_sleep(2);
            }
            __syncthreads();
        }

        {
            const uint4* hp = (const uint4*)(hbuf + (size_t)((s & 1) * B_ + g * 16) * U_);
            uint4 t0, t1, t2, t3;
            asm volatile(
                "global_load_dwordx4 %0, %4, off sc0 sc1\n\t"
                "global_load_dwordx4 %1, %5, off sc0 sc1\n\t"
                "global_load_dwordx4 %2, %6, off sc0 sc1\n\t"
                "s_waitcnt vmcnt(0)\n\t"
                "global_load_dwordx4 %3, %7, off sc0 sc1\n\t"
                "s_waitcnt vmcnt(0)"
                : "=&v"(t0), "=&v"(t1), "=&v"(t2), "=&v"(t3)
                : "v"(hp + tid), "v"(hp + tid + 256), "v"(hp + tid + 512),
                  "v"(hp + tid + 768)
                : "memory");
            int i0 = tid;        *((uint4*)&hs[i0 >> 6][(i0 & 63) * 8]) = t0;
            int i1 = tid + 256;  *((uint4*)&hs[i1 >> 6][(i1 & 63) * 8]) = t1;
            int i2 = tid + 512;  *((uint4*)&hs[i2 >> 6][(i2 & 63) * 8]) = t2;
            int i3 = tid + 768;  *((uint4*)&hs[i3 >> 6][(i3 & 63) * 8]) = t3;
        }
        __syncthreads();

        if (wave < 2) {
            f32x4 acc;
            #pragma unroll
            for (int r = 0; r < 4; ++r) acc[r] = xv[r];
            const __hip_bfloat16* arow = &hs[fn][quad * 8];
            const __hip_bfloat16* brow = &whsT[fc][quad * 8];
            #pragma unroll
            for (int kk = 0; kk < 16; ++kk) {
                bf16x8 av = *(const bf16x8*)(arow + kk * 32);
                bf16x8 bv = *(const bf16x8*)(brow + kk * 32);
                acc = __builtin_amdgcn_mfma_f32_16x16x32_bf16(av, bv, acc, 0, 0, 0);
            }
            #pragma unroll
            for (int r = 0; r < 4; ++r)
                gbuf[quad * 4 + r][fc] = acc[r];
        }
        __syncthreads();

        if (tid < 64) {
            const int m  = tid >> 2;
            const int u2 = (tid & 3) << 1;
            float gi0 = sigmoidf_(gbuf[m][u2]),      gi1 = sigmoidf_(gbuf[m][u2 + 1]);
            float gf0 = sigmoidf_(gbuf[m][8 + u2]),  gf1 = sigmoidf_(gbuf[m][9 + u2]);
            float gc0 = gbuf[m][16 + u2],            gc1 = gbuf[m][17 + u2];
            float go0 = sigmoidf_(gbuf[m][24 + u2]), go1 = sigmoidf_(gbuf[m][25 + u2]);
            float cn0 = gf0 * c0 + gi0 * fmaxf(gc0, 0.f);
            float cn1 = gf1 * c1 + gi1 * fmaxf(gc1, 0.f);
            float hn0 = go0 * fmaxf(cn0, 0.f);
            float hn1 = go1 * fmaxf(cn1, 0.f);
            if ((mask_lds[m][s >> 5] >> (s & 31)) & 1u) {
                c0 = cn0; c1 = cn1; h0 = hn0; h1 = hn1;
            }
            __hip_bfloat162 hv;
            hv.x = __float2bfloat16(h0);
            hv.y = __float2bfloat16(h1);
            unsigned wv;
            __builtin_memcpy(&wv, &hv, 4);
            unsigned* dst = (unsigned*)hbuf +
                (((((s + 1) & 1) * B_ + g * 16 + m) * U_ + u0 + u2) >> 1);
            __hip_atomic_store(dst, wv, __ATOMIC_RELAXED, __HIP_MEMORY_SCOPE_AGENT);
        }
        __syncthreads();   // implicit vmcnt(0): all h store-acks drained (release)
        if (tid == 0)
            __hip_atomic_store(&gflags[ub], s + 1, __ATOMIC_RELAXED,
                               __HIP_MEMORY_SCOPE_AGENT);
    }
}

// ---------------------------------------------------------------------------
// FC layers
// ---------------------------------------------------------------------------
__global__ __launch_bounds__(256) void fc1_kernel(const __hip_bfloat16* __restrict__ h,
                                                  const float* __restrict__ W,
                                                  const float* __restrict__ bias,
                                                  float* __restrict__ y) {
    int b = blockIdx.x >> 2, ch = blockIdx.x & 3;
    __shared__ float xrow[U_];
    for (int i = threadIdx.x; i < U_; i += 256)
        xrow[i] = __bfloat162float(h[b * U_ + i]);
    __syncthreads();
    int n = ch * 256 + threadIdx.x;
    float acc = 0.f;
    #pragma unroll 4
    for (int k = 0; k < U_; ++k) acc = fmaf(xrow[k], W[(size_t)k * D1_ + n], acc);
    y[b * D1_ + n] = fmaxf(acc + bias[n], 0.f);
}

__global__ __launch_bounds__(256) void fc2_kernel(const float* __restrict__ x,
                                                  const float* __restrict__ W,
                                                  const float* __restrict__ bias,
                                                  float* __restrict__ y) {
    int b = blockIdx.x >> 2, ch = blockIdx.x & 3;
    __shared__ float xrow[D1_];
    for (int i = threadIdx.x; i < D1_; i += 256) xrow[i] = x[b * D1_ + i];
    __syncthreads();
    int n = ch * 256 + threadIdx.x;
    float acc = 0.f;
    #pragma unroll 4
    for (int k = 0; k < D1_; ++k) acc = fmaf(xrow[k], W[(size_t)k * D2_ + n], acc);
    y[b * D2_ + n] = fmaxf(acc + bias[n], 0.f);
}

// ---------------------------------------------------------------------------
// logits + softmax
// ---------------------------------------------------------------------------
__global__ __launch_bounds__(64) void out_kernel(const float* __restrict__ h2,
                                                 const float* __restrict__ Wo,
                                                 const float* __restrict__ bo,
                                                 float* __restrict__ out) {
    int b = blockIdx.x;
    __shared__ float xrow[D2_];
    __shared__ float lg[NC_];
    __shared__ float red[2];
    for (int i = threadIdx.x; i < D2_; i += 64) xrow[i] = h2[b * D2_ + i];
    __syncthreads();
    if (threadIdx.x < NC_) {
        float a = bo[threadIdx.x];
        for (int k = 0; k < D2_; ++k) a = fmaf(xrow[k], Wo[k * NC_ + threadIdx.x], a);
        lg[threadIdx.x] = a;
    }
    __syncthreads();
    if (threadIdx.x == 0) {
        float mx = lg[0];
        for (int c = 1; c < NC_; ++c) mx = fmaxf(mx, lg[c]);
        float sm = 0.f;
        for (int c = 0; c < NC_; ++c) sm += expf(lg[c] - mx);
        red[0] = mx; red[1] = 1.0f / sm;
    }
    __syncthreads();
    if (threadIdx.x < NC_)
        out[b * NC_ + threadIdx.x] = expf(lg[threadIdx.x] - red[0]) * red[1];
}

// ---------------------------------------------------------------------------
extern "C" void kernel_launch(void* const* d_in, const int* in_sizes, int n_in,
                              void* d_out, int out_size, void* d_ws, size_t ws_size,
                              hipStream_t stream) {
    const int*   tokens = (const int*)d_in[0];
    const float* emb    = (const float*)d_in[1];
    const float* Wx     = (const float*)d_in[2];
    const float* Wh     = (const float*)d_in[3];
    const float* b      = (const float*)d_in[4];
    const float* W1     = (const float*)d_in[5];
    const float* b1     = (const float*)d_in[6];
    const float* W2     = (const float*)d_in[7];
    const float* b2     = (const float*)d_in[8];
    const float* Wo     = (const float*)d_in[9];
    const float* bo     = (const float*)d_in[10];
    float* out = (float*)d_out;

    char* ws = (char*)d_ws;
    const size_t XG_BYTES   = (size_t)T_ * B_ * G4_ * 2;        // 134,217,728
    const size_t HBUF_BYTES = (size_t)2 * B_ * U_ * 2;          // 131,072
    __hip_bfloat16* xg   = (__hip_bfloat16*)ws;
    __hip_bfloat16* hbuf = (__hip_bfloat16*)(ws + XG_BYTES);
    int* flags           = (int*)(ws + XG_BYTES + HBUF_BYTES);
    char* p = ws + XG_BYTES + HBUF_BYTES + 1024;
    float* h1            = (float*)p;                 p += (size_t)B_ * D1_ * 4;
    float* h2            = (float*)p;                 p += (size_t)B_ * D2_ * 4;
    __hip_bfloat16* xb   = (__hip_bfloat16*)p;        p += (size_t)B_ * T_ * KP_ * 2;
    __hip_bfloat16* wxT  = (__hip_bfloat16*)p;        // 2048*320*2 = 1.3 MB

    init_kernel<<<64, 256, 0, stream>>>((unsigned int*)hbuf, flags);
    prep_wxT<<<dim3(32, 5), 256, 0, stream>>>(Wx, wxT);
    prep_xb<<<(B_ * T_) / 4, 256, 0, stream>>>(tokens, emb, xb);
    xg_gemm<<<dim3(16, 256), 256, 0, stream>>>(xb, wxT, b, xg);
    lstm_kernel<<<256, 256, 0, stream>>>(xg, tokens, Wh, hbuf, flags);
    fc1_kernel<<<256, 256, 0, stream>>>(hbuf, W1, b1, h1);
    fc2_kernel<<<256, 256, 0, stream>>>(h1, W2, b2, h2);
    out_kernel<<<64, 64, 0, stream>>>(h2, Wo, bo, out);
}